// Round 4
// baseline (247.333 us; speedup 1.0000x reference)
//
#include <hip/hip_runtime.h>
#include <hip/hip_bf16.h>

#pragma clang fp contract(off)

#define HH 96
#define WW 96
#define KK 16
#define MM 2
#define NF 512          // M * Fm
#define NV 512          // M * V
#define NPIX (HH*WW)    // 9216
#define PPB 256         // pixels per block

__device__ __forceinline__ float edge_d2(float px, float py,
                                         float ax, float ay,
                                         float bx, float by) {
    float abx = bx - ax, aby = by - ay;
    float apx = px - ax, apy = py - ay;
    float t = (apx*abx + apy*aby) / (abx*abx + aby*aby + 1e-12f);
    t = fminf(fmaxf(t, 0.0f), 1.0f);
    float dx = apx - t*abx, dy = apy - t*aby;
    return dx*dx + dy*dy;
}

// constants (match the Python reference)
#define SIGMA_F 1e-4f
#define GAMMA_F 1e-4f
#define BLUR_F  9.210240366975851e-4f   // log(1/1e-4 - 1) * 1e-4 -> f32
#define EPS_F   1e-10f
#define ZFAR_F  100.0f
#define ZNEAR_F 1.0f

struct Rast {
    float b0, b1, b2, zpix, dists;
};

__device__ __forceinline__ Rast rasterize(float px, float py,
                                          float4 q0, float4 q1, float z2v) {
    Rast r;
    float v0x=q0.x, v0y=q0.y, v1x=q0.z, v1y=q0.w, v2x=q1.x, v2y=q1.y;
    float z0=q1.z, z1=q1.w;
    float e1x=v1x-v0x, e1y=v1y-v0y, e2x=v2x-v0x, e2y=v2y-v0y;
    float dx=px-v0x, dy=py-v0y;
    float den = e1x*e2y - e1y*e2x + 1e-12f;
    r.b1 = (dx*e2y - dy*e2x) / den;
    r.b2 = (e1x*dy - e1y*dx) / den;
    r.b0 = 1.0f - r.b1 - r.b2;
    r.zpix = r.b0*z0 + r.b1*z1 + r.b2*z2v;
    bool inside = (r.b0 >= 0.0f) && (r.b1 >= 0.0f) && (r.b2 >= 0.0f);
    float d2 = edge_d2(px, py, v0x, v0y, v1x, v1y);
    d2 = fminf(d2, edge_d2(px, py, v1x, v1y, v2x, v2y));
    d2 = fminf(d2, edge_d2(px, py, v2x, v2y, v0x, v0y));
    r.dists = inside ? -d2 : d2;
    return r;
}

__global__ __launch_bounds__(256) void render_kernel(
    const float* __restrict__ mpos,    // (B,M,3)
    const float* __restrict__ mrot,    // (B,M,3,3)
    const float* __restrict__ mscale,  // (B,M,3)
    const float* __restrict__ cpos,    // (B,3)
    const float* __restrict__ crot,    // (B,3,3)
    const float* __restrict__ verts,   // (M,V,3)
    const int*   __restrict__ faces,   // (M,Fm,3)
    const float* __restrict__ vcol,    // (M,V,3)
    float*       __restrict__ out)     // (B,H,W,4)
{
    __shared__ float svx[NV], svy[NV], svz[NV];
    __shared__ float4 sface[NF][5];

    const int blocksPerBatch = NPIX / PPB;           // 36
    const int b    = blockIdx.x / blocksPerBatch;
    const int tile = blockIdx.x % blocksPerBatch;
    const int tid  = threadIdx.x;

    // camera for this batch
    float cr[9];
    #pragma unroll
    for (int t = 0; t < 9; ++t) cr[t] = crot[b*9 + t];
    const float cpx = cpos[b*3+0];
    const float cpy = cpos[b*3+1];
    const float cpz = cpos[b*3+2];

    // ---- phase 1: vertex transform -> screen xy + cam z, in LDS ----
    for (int g = tid; g < NV; g += PPB) {
        int m = g >> 8;                    // V = 256
        int sb = (b*MM + m)*3;
        float s0 = mscale[sb+0];
        float s1 = mscale[sb+1];
        float s2 = mscale[sb+2];
        float v0 = verts[g*3+0] * s0;
        float v1 = verts[g*3+1] * s1;
        float v2 = verts[g*3+2] * s2;
        int rb = (b*MM + m)*9;
        float wx = mrot[rb+0]*v0 + mrot[rb+1]*v1 + mrot[rb+2]*v2 + mpos[sb+0];
        float wy = mrot[rb+3]*v0 + mrot[rb+4]*v1 + mrot[rb+5]*v2 + mpos[sb+1];
        float wz = mrot[rb+6]*v0 + mrot[rb+7]*v1 + mrot[rb+8]*v2 + mpos[sb+2];
        // cam_i = sum_j world_j * crot[j][i] + cpos_i
        float cx = wx*cr[0] + wy*cr[3] + wz*cr[6] + cpx;
        float cy = wx*cr[1] + wy*cr[4] + wz*cr[7] + cpy;
        float cz = wx*cr[2] + wy*cr[5] + wz*cr[8] + cpz;
        svx[g] = cx / cz;
        svy[g] = cy / cz;
        svz[g] = cz;
    }
    __syncthreads();

    // ---- phase 2: per-face gather into LDS (5 x float4 each, 80 B) ----
    for (int f = tid; f < NF; f += PPB) {
        int m = f >> 8;                    // Fm = 256
        int off = m << 8;                  // m * V
        int i0 = faces[f*3+0] + off;
        int i1 = faces[f*3+1] + off;
        int i2 = faces[f*3+2] + off;
        sface[f][0] = make_float4(svx[i0], svy[i0], svx[i1], svy[i1]);
        sface[f][1] = make_float4(svx[i2], svy[i2], svz[i0], svz[i1]);
        sface[f][2] = make_float4(svz[i2],
                                  vcol[i0*3+0], vcol[i0*3+1], vcol[i0*3+2]);
        sface[f][3] = make_float4(vcol[i1*3+0], vcol[i1*3+1], vcol[i1*3+2],
                                  vcol[i2*3+0]);
        sface[f][4] = make_float4(vcol[i2*3+1], vcol[i2*3+2], 0.0f, 0.0f);
    }
    __syncthreads();

    // ---- phase 3: rasterize one pixel per thread ----
    const int p  = tile * PPB + tid;
    const int pi = p / WW, pj = p % WW;
    const float px = ((float)pj + 0.5f) * 2.0f / (float)WW - 1.0f;
    const float py = 1.0f - ((float)pi + 0.5f) * 2.0f / (float)HH;

    float topZ[KK];
    int   topI[KK];
    #pragma unroll
    for (int s = 0; s < KK; ++s) { topZ[s] = INFINITY; topI[s] = -1; }
    float curMax = INFINITY;

    for (int f = 0; f < NF; ++f) {
        float4 q0 = sface[f][0];
        float4 q1 = sface[f][1];
        float4 q2 = sface[f][2];
        Rast r = rasterize(px, py, q0, q1, q2.x);
        bool valid = (r.zpix > 0.01f) && (r.dists <= BLUR_F);
        if (valid && (r.zpix < curMax)) {
            // replace the current-max slot (fills INF slots first)
            float mz = topZ[0]; int mslot = 0;
            #pragma unroll
            for (int s = 1; s < KK; ++s) {
                if (topZ[s] > mz) { mz = topZ[s]; mslot = s; }
            }
            #pragma unroll
            for (int s = 0; s < KK; ++s) {
                if (s == mslot) { topZ[s] = r.zpix; topI[s] = f; }
            }
            curMax = topZ[0];
            #pragma unroll
            for (int s = 1; s < KK; ++s) curMax = fmaxf(curMax, topZ[s]);
        }
    }

    // ---- phase 4: soft aggregation over the selected K ----
    float zmaxv = EPS_F;
    #pragma unroll
    for (int s = 0; s < KK; ++s) {
        if (topI[s] >= 0) {
            float zinv = (ZFAR_F - topZ[s]) / (ZFAR_F - ZNEAR_F);
            zmaxv = fmaxf(zmaxv, zinv);
        }
    }
    float delta = expf((EPS_F - zmaxv) / GAMMA_F);
    float numr = delta, numg = delta, numb = delta;   // bg = (1,1,1)
    float denom = delta;
    float alpha_prod = 1.0f;

    #pragma unroll
    for (int s = 0; s < KK; ++s) {
        int f = topI[s];
        if (f < 0) continue;
        float4 q0 = sface[f][0];
        float4 q1 = sface[f][1];
        float4 q2 = sface[f][2];
        float4 q3 = sface[f][3];
        float4 q4 = sface[f][4];
        Rast r = rasterize(px, py, q0, q1, q2.x);
        // prob = sigmoid(-dists/SIGMA) = 1/(1+exp(dists/SIGMA)); dists <= BLUR so stable
        float prob = 1.0f / (1.0f + expf(r.dists / SIGMA_F));
        float zinv = (ZFAR_F - topZ[s]) / (ZFAR_F - ZNEAR_F);
        float w = prob * expf((zinv - zmaxv) / GAMMA_F);
        float tr = r.b0*q2.y + r.b1*q3.x + r.b2*q3.w;
        float tg = r.b0*q2.z + r.b1*q3.y + r.b2*q4.x;
        float tb = r.b0*q2.w + r.b1*q3.z + r.b2*q4.y;
        numr += w * tr;
        numg += w * tg;
        numb += w * tb;
        denom += w;
        alpha_prod *= (1.0f - prob);
    }

    float4 px4;
    px4.x = numr / denom;
    px4.y = numg / denom;
    px4.z = numb / denom;
    px4.w = 1.0f - alpha_prod;
    *reinterpret_cast<float4*>(&out[((size_t)b * NPIX + p) * 4]) = px4;
}

extern "C" void kernel_launch(void* const* d_in, const int* in_sizes, int n_in,
                              void* d_out, int out_size, void* d_ws, size_t ws_size,
                              hipStream_t stream) {
    const float* mpos   = (const float*)d_in[0];
    const float* mrot   = (const float*)d_in[1];
    const float* mscale = (const float*)d_in[2];
    const float* cpos   = (const float*)d_in[3];
    const float* crot   = (const float*)d_in[4];
    const float* verts  = (const float*)d_in[5];
    const int*   faces  = (const int*)d_in[6];
    const float* vcol   = (const float*)d_in[7];
    float*       out    = (float*)d_out;

    const int B = in_sizes[3] / 3;                  // cam_pos is (B,3)
    const int blocksPerBatch = NPIX / PPB;          // 36
    dim3 grid(B * blocksPerBatch), block(PPB);
    render_kernel<<<grid, block, 0, stream>>>(mpos, mrot, mscale, cpos, crot,
                                              verts, faces, vcol, out);
}

// Round 5
// 149.786 us; speedup vs baseline: 1.6512x; 1.6512x over previous
//
#include <hip/hip_runtime.h>
#include <hip/hip_bf16.h>

#pragma clang fp contract(off)

#define HH 96
#define WW 96
#define KK 16
#define MM 2
#define NF 512            // M * Fm
#define NV 512            // M * V
#define NPIX (HH*WW)      // 9216
#define PIX_PB 32         // pixels per block
#define TPP 8             // threads (subs) per pixel
#define FPT (NF/TPP)      // 64 faces per thread

#define SIGMA_F 1e-4f
#define GAMMA_F 1e-4f
#define BLUR_F  9.210240366975851e-4f   // log(1/1e-4 - 1) * 1e-4 -> f32
#define EPS_F   1e-10f
#define ZFAR_F  100.0f
#define ZNEAR_F 1.0f

__device__ __forceinline__ float edge_d2(float px, float py,
                                         float ax, float ay,
                                         float bx, float by) {
    float abx = bx - ax, aby = by - ay;
    float apx = px - ax, apy = py - ay;
    float t = (apx*abx + apy*aby) / (abx*abx + aby*aby + 1e-12f);
    t = fminf(fmaxf(t, 0.0f), 1.0f);
    float dx = apx - t*abx, dy = apy - t*aby;
    return dx*dx + dy*dy;
}

__device__ __forceinline__ unsigned long long packzf(float z, int f) {
    return (((unsigned long long)__float_as_uint(z)) << 32) | (unsigned int)f;
}

struct Rast { float b0, b1, b2, zpix, dists; };

__device__ __forceinline__ Rast rasterize(float px, float py,
                                          float4 P0, float4 P1, float4 P2) {
    Rast r;
    float e1x = P1.x-P0.x, e1y = P1.y-P0.y;
    float e2x = P2.x-P0.x, e2y = P2.y-P0.y;
    float dx = px-P0.x, dy = py-P0.y;
    float den = e1x*e2y - e1y*e2x + 1e-12f;
    r.b1 = (dx*e2y - dy*e2x) / den;
    r.b2 = (e1x*dy - e1y*dx) / den;
    r.b0 = 1.0f - r.b1 - r.b2;
    r.zpix = r.b0*P0.z + r.b1*P1.z + r.b2*P2.z;
    bool inside = (r.b0 >= 0.0f) && (r.b1 >= 0.0f) && (r.b2 >= 0.0f);
    float d2 = edge_d2(px, py, P0.x, P0.y, P1.x, P1.y);
    d2 = fminf(d2, edge_d2(px, py, P1.x, P1.y, P2.x, P2.y));
    d2 = fminf(d2, edge_d2(px, py, P2.x, P2.y, P0.x, P0.y));
    r.dists = inside ? -d2 : d2;
    return r;
}

__global__ __launch_bounds__(256) void render_kernel(
    const float* __restrict__ mpos,    // (B,M,3)
    const float* __restrict__ mrot,    // (B,M,3,3)
    const float* __restrict__ mscale,  // (B,M,3)
    const float* __restrict__ cpos,    // (B,3)
    const float* __restrict__ crot,    // (B,3,3)
    const float* __restrict__ verts,   // (M,V,3)
    const int*   __restrict__ faces,   // (M,Fm,3)
    const float* __restrict__ vcol,    // (M,V,3)
    float*       __restrict__ out)     // (B,H,W,4)
{
    __shared__ float4 svp[NV];                              // 8 KB  (x, y, z, pad)
    __shared__ unsigned long long cand[TPP][KK][PIX_PB];    // 32 KB (pixel-minor: 2-way max)
    __shared__ int   scnt[TPP][PIX_PB];                     // 1 KB
    __shared__ float sminz[TPP][PIX_PB];                    // 1 KB
    __shared__ float spart[5][TPP][PIX_PB];                 // 5 KB

    const int blocksPerBatch = NPIX / PIX_PB;               // 288
    const int b    = blockIdx.x / blocksPerBatch;
    const int tile = blockIdx.x % blocksPerBatch;
    const int tid  = threadIdx.x;
    const int pix  = tid & (PIX_PB - 1);                    // 0..31
    const int sub  = tid >> 5;                              // 0..7

    // camera for this batch
    float cr[9];
    #pragma unroll
    for (int t = 0; t < 9; ++t) cr[t] = crot[b*9 + t];
    const float cpx = cpos[b*3+0];
    const float cpy = cpos[b*3+1];
    const float cpz = cpos[b*3+2];

    // ---- phase 1: vertex transform -> screen xy + cam z, in LDS ----
    for (int g = tid; g < NV; g += 256) {
        int m = g >> 8;                    // V = 256
        int sb = (b*MM + m)*3;
        float s0 = mscale[sb+0];
        float s1 = mscale[sb+1];
        float s2 = mscale[sb+2];
        float v0 = verts[g*3+0] * s0;
        float v1 = verts[g*3+1] * s1;
        float v2 = verts[g*3+2] * s2;
        int rb = (b*MM + m)*9;
        float wx = mrot[rb+0]*v0 + mrot[rb+1]*v1 + mrot[rb+2]*v2 + mpos[sb+0];
        float wy = mrot[rb+3]*v0 + mrot[rb+4]*v1 + mrot[rb+5]*v2 + mpos[sb+1];
        float wz = mrot[rb+6]*v0 + mrot[rb+7]*v1 + mrot[rb+8]*v2 + mpos[sb+2];
        float cx = wx*cr[0] + wy*cr[3] + wz*cr[6] + cpx;
        float cy = wx*cr[1] + wy*cr[4] + wz*cr[7] + cpy;
        float cz = wx*cr[2] + wy*cr[5] + wz*cr[8] + cpz;
        svp[g] = make_float4(cx / cz, cy / cz, cz, 0.0f);
    }
    __syncthreads();

    // ---- phase 2: scan this sub's 64 faces, keep register top-16 ----
    const int p  = tile * PIX_PB + pix;
    const int pi = p / WW, pj = p % WW;
    const float px = ((float)pj + 0.5f) * 2.0f / (float)WW - 1.0f;
    const float py = 1.0f - ((float)pi + 0.5f) * 2.0f / (float)HH;

    float topZ[KK];
    int   topI[KK];
    #pragma unroll
    for (int s = 0; s < KK; ++s) { topZ[s] = INFINITY; topI[s] = -1; }
    float curMax = INFINITY;

    for (int k = 0; k < FPT; ++k) {
        const int f = sub * FPT + k;          // uniform across the 32 lanes of a half-wave
        const int moff = (f >> 8) << 8;       // mesh m * V
        int i0 = faces[f*3+0] + moff;
        int i1 = faces[f*3+1] + moff;
        int i2 = faces[f*3+2] + moff;
        float4 P0 = svp[i0];                  // LDS broadcast reads (addr uniform/half-wave)
        float4 P1 = svp[i1];
        float4 P2 = svp[i2];
        Rast r = rasterize(px, py, P0, P1, P2);
        bool valid = (r.zpix > 0.01f) && (r.dists <= BLUR_F) && (r.zpix < curMax);
        if (valid) {
            float mz = topZ[0]; int mslot = 0;
            #pragma unroll
            for (int s = 1; s < KK; ++s)
                if (topZ[s] > mz) { mz = topZ[s]; mslot = s; }
            #pragma unroll
            for (int s = 0; s < KK; ++s)
                if (s == mslot) { topZ[s] = r.zpix; topI[s] = f; }
            curMax = topZ[0];
            #pragma unroll
            for (int s = 1; s < KK; ++s) curMax = fmaxf(curMax, topZ[s]);
        }
    }

    // ---- phase 3: publish candidates (deterministic, fixed regions) ----
    {
        int c = 0;
        float mn = INFINITY;
        #pragma unroll
        for (int s = 0; s < KK; ++s) {
            if (topI[s] >= 0) {
                cand[sub][c][pix] = packzf(topZ[s], topI[s]);
                ++c;
                mn = fminf(mn, topZ[s]);
            }
        }
        scnt[sub][pix]  = c;
        sminz[sub][pix] = mn;
    }
    __syncthreads();

    // ---- phase 4: per-sub aggregation of its own included candidates ----
    int total = 0;
    #pragma unroll
    for (int s = 0; s < TPP; ++s) total += scnt[s][pix];

    float minz = INFINITY;
    #pragma unroll
    for (int s = 0; s < TPP; ++s) minz = fminf(minz, sminz[s][pix]);

    float zmaxv = EPS_F;
    if (minz < INFINITY)
        zmaxv = fmaxf((ZFAR_F - minz) / (ZFAR_F - ZNEAR_F), EPS_F);

    float nr = 0.0f, ng = 0.0f, nb = 0.0f, dn = 0.0f, ap = 1.0f;

    #pragma unroll
    for (int s = 0; s < KK; ++s) {
        int f = topI[s];
        if (f < 0) continue;
        bool inc = true;
        if (total > KK) {
            unsigned long long mypk = packzf(topZ[s], f);
            int rank = 0;
            for (int t = 0; t < TPP; ++t) {
                int n = scnt[t][pix];
                for (int j = 0; j < n; ++j)
                    rank += (cand[t][j][pix] < mypk) ? 1 : 0;
            }
            inc = (rank < KK);
        }
        if (!inc) continue;

        const int moff = (f >> 8) << 8;
        int i0 = faces[f*3+0] + moff;
        int i1 = faces[f*3+1] + moff;
        int i2 = faces[f*3+2] + moff;
        float4 P0 = svp[i0];
        float4 P1 = svp[i1];
        float4 P2 = svp[i2];
        Rast r = rasterize(px, py, P0, P1, P2);

        float prob = 1.0f / (1.0f + expf(r.dists / SIGMA_F));
        float zinv = (ZFAR_F - topZ[s]) / (ZFAR_F - ZNEAR_F);
        float w = prob * expf((zinv - zmaxv) / GAMMA_F);
        float tr = r.b0*vcol[i0*3+0] + r.b1*vcol[i1*3+0] + r.b2*vcol[i2*3+0];
        float tg = r.b0*vcol[i0*3+1] + r.b1*vcol[i1*3+1] + r.b2*vcol[i2*3+1];
        float tb = r.b0*vcol[i0*3+2] + r.b1*vcol[i1*3+2] + r.b2*vcol[i2*3+2];
        nr += w * tr;
        ng += w * tg;
        nb += w * tb;
        dn += w;
        ap *= (1.0f - prob);
    }

    spart[0][sub][pix] = nr;
    spart[1][sub][pix] = ng;
    spart[2][sub][pix] = nb;
    spart[3][sub][pix] = dn;
    spart[4][sub][pix] = ap;
    __syncthreads();

    // ---- phase 5: fixed-order reduction + output (one thread per pixel) ----
    if (tid < PIX_PB) {
        float rr = 0.0f, gg = 0.0f, bb = 0.0f, dd = 0.0f, aa = 1.0f;
        #pragma unroll
        for (int s = 0; s < TPP; ++s) {
            rr += spart[0][s][tid];
            gg += spart[1][s][tid];
            bb += spart[2][s][tid];
            dd += spart[3][s][tid];
            aa *= spart[4][s][tid];
        }
        float mz = INFINITY;
        #pragma unroll
        for (int s = 0; s < TPP; ++s) mz = fminf(mz, sminz[s][tid]);
        float zmx = EPS_F;
        if (mz < INFINITY)
            zmx = fmaxf((ZFAR_F - mz) / (ZFAR_F - ZNEAR_F), EPS_F);
        float delta = expf((EPS_F - zmx) / GAMMA_F);
        rr += delta; gg += delta; bb += delta; dd += delta;

        int pp = tile * PIX_PB + tid;
        float4 px4;
        px4.x = rr / dd;
        px4.y = gg / dd;
        px4.z = bb / dd;
        px4.w = 1.0f - aa;
        *reinterpret_cast<float4*>(&out[((size_t)b * NPIX + pp) * 4]) = px4;
    }
}

extern "C" void kernel_launch(void* const* d_in, const int* in_sizes, int n_in,
                              void* d_out, int out_size, void* d_ws, size_t ws_size,
                              hipStream_t stream) {
    const float* mpos   = (const float*)d_in[0];
    const float* mrot   = (const float*)d_in[1];
    const float* mscale = (const float*)d_in[2];
    const float* cpos   = (const float*)d_in[3];
    const float* crot   = (const float*)d_in[4];
    const float* verts  = (const float*)d_in[5];
    const int*   faces  = (const int*)d_in[6];
    const float* vcol   = (const float*)d_in[7];
    float*       out    = (float*)d_out;

    const int B = in_sizes[3] / 3;                  // cam_pos is (B,3)
    const int blocksPerBatch = NPIX / PIX_PB;       // 288
    dim3 grid(B * blocksPerBatch), block(256);
    render_kernel<<<grid, block, 0, stream>>>(mpos, mrot, mscale, cpos, crot,
                                              verts, faces, vcol, out);
}

// Round 6
// 47.870 us; speedup vs baseline: 5.1667x; 3.1290x over previous
//
#include <hip/hip_runtime.h>

#pragma clang fp contract(off)

#define HH 96
#define WW 96
#define KK 16
#define MM 2
#define NF 512            // M * Fm
#define NV 512            // M * V
#define NPIX (HH*WW)      // 9216

#define SIGMA_F 1e-4f
#define GAMMA_F 1e-4f
#define BLUR_F  9.210240366975851e-4f   // log(1/1e-4 - 1) * 1e-4 -> f32
#define EPS_F   1e-10f
#define ZFAR_F  100.0f
#define ZNEAR_F 1.0f
#define RM      0.0304f                 // > sqrt(BLUR_F) = 0.0303484; conservative margin

#define SENT 0xFFFFFFFFFFFFFFFFull

__device__ __forceinline__ float frcp(float x) { return __builtin_amdgcn_rcpf(x); }

__device__ __forceinline__ float edge_d2(float px, float py,
                                         float ax, float ay,
                                         float bx, float by) {
    float abx = bx - ax, aby = by - ay;
    float apx = px - ax, apy = py - ay;
    float t = (apx*abx + apy*aby) * frcp(abx*abx + aby*aby + 1e-12f);
    t = fminf(fmaxf(t, 0.0f), 1.0f);
    float dx = apx - t*abx, dy = apy - t*aby;
    return dx*dx + dy*dy;
}

struct Rast { float b0, b1, b2, zpix, dists; };

// geo-packed layout: g0=(x0,y0,x1,y1) g1=(x2,y2,z0,z1) g2=(z2,-,-,-)
__device__ __forceinline__ Rast rasterize_g(float px, float py,
                                            float4 g0, float4 g1, float4 g2) {
    Rast r;
    float v0x=g0.x, v0y=g0.y, v1x=g0.z, v1y=g0.w, v2x=g1.x, v2y=g1.y;
    float z0=g1.z, z1=g1.w, z2=g2.x;
    float e1x=v1x-v0x, e1y=v1y-v0y, e2x=v2x-v0x, e2y=v2y-v0y;
    float dx=px-v0x, dy=py-v0y;
    float rden = frcp(e1x*e2y - e1y*e2x + 1e-12f);
    r.b1 = (dx*e2y - dy*e2x) * rden;
    r.b2 = (e1x*dy - e1y*dx) * rden;
    r.b0 = 1.0f - r.b1 - r.b2;
    r.zpix = r.b0*z0 + r.b1*z1 + r.b2*z2;
    bool inside = (r.b0 >= 0.0f) && (r.b1 >= 0.0f) && (r.b2 >= 0.0f);
    float d2 = edge_d2(px, py, v0x, v0y, v1x, v1y);
    d2 = fminf(d2, edge_d2(px, py, v1x, v1y, v2x, v2y));
    d2 = fminf(d2, edge_d2(px, py, v2x, v2y, v0x, v0y));
    r.dists = inside ? -d2 : d2;
    return r;
}

// xyz-float4 layout (fallback kernel)
__device__ __forceinline__ Rast rasterize_p(float px, float py,
                                            float4 P0, float4 P1, float4 P2) {
    Rast r;
    float e1x = P1.x-P0.x, e1y = P1.y-P0.y;
    float e2x = P2.x-P0.x, e2y = P2.y-P0.y;
    float dx = px-P0.x, dy = py-P0.y;
    float rden = frcp(e1x*e2y - e1y*e2x + 1e-12f);
    r.b1 = (dx*e2y - dy*e2x) * rden;
    r.b2 = (e1x*dy - e1y*dx) * rden;
    r.b0 = 1.0f - r.b1 - r.b2;
    r.zpix = r.b0*P0.z + r.b1*P1.z + r.b2*P2.z;
    bool inside = (r.b0 >= 0.0f) && (r.b1 >= 0.0f) && (r.b2 >= 0.0f);
    float d2 = edge_d2(px, py, P0.x, P0.y, P1.x, P1.y);
    d2 = fminf(d2, edge_d2(px, py, P1.x, P1.y, P2.x, P2.y));
    d2 = fminf(d2, edge_d2(px, py, P2.x, P2.y, P0.x, P0.y));
    r.dists = inside ? -d2 : d2;
    return r;
}

__device__ __forceinline__ unsigned long long packzf(float z, int f) {
    return (((unsigned long long)__float_as_uint(z)) << 32) | (unsigned int)f;
}

__device__ __forceinline__ unsigned long long shflx64(unsigned long long v, int m) {
    int lo = __shfl_xor((int)(unsigned)(v & 0xffffffffull), m, 64);
    int hi = __shfl_xor((int)(unsigned)(v >> 32), m, 64);
    return ((unsigned long long)(unsigned)hi << 32) | (unsigned)lo;
}

__device__ __forceinline__ void agg_face(float px, float py,
                                         const float4* __restrict__ geop,
                                         const float4* __restrict__ colp,
                                         int bf, float z, float zmaxv,
                                         float& nr, float& ng, float& nb,
                                         float& dn, float& ap) {
    float4 g0 = geop[bf*3+0], g1 = geop[bf*3+1], g2 = geop[bf*3+2];
    Rast r = rasterize_g(px, py, g0, g1, g2);
    float prob = 1.0f / (1.0f + expf(r.dists / SIGMA_F));
    float zinv = (ZFAR_F - z) / (ZFAR_F - ZNEAR_F);
    float w = prob * expf((zinv - zmaxv) / GAMMA_F);
    float4 c0 = colp[bf*3+0], c1 = colp[bf*3+1], c2 = colp[bf*3+2];
    nr += w * (r.b0*c0.x + r.b1*c1.x + r.b2*c2.x);
    ng += w * (r.b0*c0.y + r.b1*c1.y + r.b2*c2.y);
    nb += w * (r.b0*c0.z + r.b1*c1.z + r.b2*c2.z);
    dn += w;
    ap *= (1.0f - prob);
}

// ============ kernel 1: stage per-(b,face) bbox/geo/col records into ws ============
__global__ void stage_kernel(
    const float* __restrict__ mpos, const float* __restrict__ mrot,
    const float* __restrict__ mscale, const float* __restrict__ cpos,
    const float* __restrict__ crot, const float* __restrict__ verts,
    const int* __restrict__ faces, const float* __restrict__ vcol,
    float4* __restrict__ ws)
{
    const int b = blockIdx.x / MM, m = blockIdx.x % MM, t = threadIdx.x;
    const int B = gridDim.x / MM;
    const int BF = B * NF;
    __shared__ float sx[256], sy[256], sz[256];

    float cr[9];
    #pragma unroll
    for (int i = 0; i < 9; ++i) cr[i] = crot[b*9 + i];
    const float cpx = cpos[b*3+0], cpy = cpos[b*3+1], cpz = cpos[b*3+2];

    {
        int sb = (b*MM + m)*3, rb = (b*MM + m)*9;
        int vid = m*256 + t;
        float v0 = verts[vid*3+0] * mscale[sb+0];
        float v1 = verts[vid*3+1] * mscale[sb+1];
        float v2 = verts[vid*3+2] * mscale[sb+2];
        float wx = mrot[rb+0]*v0 + mrot[rb+1]*v1 + mrot[rb+2]*v2 + mpos[sb+0];
        float wy = mrot[rb+3]*v0 + mrot[rb+4]*v1 + mrot[rb+5]*v2 + mpos[sb+1];
        float wz = mrot[rb+6]*v0 + mrot[rb+7]*v1 + mrot[rb+8]*v2 + mpos[sb+2];
        float cx = wx*cr[0] + wy*cr[3] + wz*cr[6] + cpx;
        float cy = wx*cr[1] + wy*cr[4] + wz*cr[7] + cpy;
        float cz = wx*cr[2] + wy*cr[5] + wz*cr[8] + cpz;
        sx[t] = cx / cz;  sy[t] = cy / cz;  sz[t] = cz;
    }
    __syncthreads();

    const int fb = (m*256 + t)*3;
    const int i0 = faces[fb+0], i1 = faces[fb+1], i2 = faces[fb+2];
    const float x0 = sx[i0], y0 = sy[i0], z0 = sz[i0];
    const float x1 = sx[i1], y1 = sy[i1], z1 = sz[i1];
    const float x2 = sx[i2], y2 = sy[i2], z2 = sz[i2];

    const int bf = b*NF + m*256 + t;
    float4* bboxp = ws;
    float4* geop  = ws + BF;
    float4* colp  = ws + 4*BF;

    bboxp[bf] = make_float4(fminf(fminf(x0,x1),x2), fminf(fminf(y0,y1),y2),
                            fmaxf(fmaxf(x0,x1),x2), fmaxf(fmaxf(y0,y1),y2));
    geop[bf*3+0] = make_float4(x0, y0, x1, y1);
    geop[bf*3+1] = make_float4(x2, y2, z0, z1);
    geop[bf*3+2] = make_float4(z2, 0.0f, 0.0f, 0.0f);

    int c0i = (m*256 + i0)*3, c1i = (m*256 + i1)*3, c2i = (m*256 + i2)*3;
    colp[bf*3+0] = make_float4(vcol[c0i], vcol[c0i+1], vcol[c0i+2], 0.0f);
    colp[bf*3+1] = make_float4(vcol[c1i], vcol[c1i+1], vcol[c1i+2], 0.0f);
    colp[bf*3+2] = make_float4(vcol[c2i], vcol[c2i+1], vcol[c2i+2], 0.0f);
}

// ============ kernel 2: wave-per-pixel render ============
__global__ __launch_bounds__(256) void render_wave_kernel(
    const float4* __restrict__ ws, float* __restrict__ out, int B)
{
    const int tilesPerB = NPIX / 4;                 // 2304 blocks per batch (4 waves each)
    const int b    = blockIdx.x / tilesPerB;
    const int tile = blockIdx.x % tilesPerB;
    const int wv   = threadIdx.x >> 6;
    const int lane = threadIdx.x & 63;
    const int p    = tile*4 + wv;
    const int pi = p / WW, pj = p % WW;
    const float px = ((float)pj + 0.5f) * 2.0f / (float)WW - 1.0f;
    const float py = 1.0f - ((float)pi + 0.5f) * 2.0f / (float)HH;

    const int BF = B * NF;
    const float4* bboxp = ws;
    const float4* geop  = ws + BF;
    const float4* colp  = ws + 4*BF;
    const int base = b * NF;

    // ---- scan: 8 static slots per lane, bbox prefilter ----
    unsigned long long pk[8];
    int validm = 0;
    #pragma unroll
    for (int k = 0; k < 8; ++k) {
        int f  = (k << 6) | lane;
        int bf = base + f;
        float4 bb = bboxp[bf];
        unsigned long long t = SENT;
        if (px >= bb.x - RM && px <= bb.z + RM &&
            py >= bb.y - RM && py <= bb.w + RM) {
            float4 g0 = geop[bf*3+0], g1 = geop[bf*3+1], g2 = geop[bf*3+2];
            Rast r = rasterize_g(px, py, g0, g1, g2);
            if (r.zpix > 0.01f && r.dists <= BLUR_F) t = packzf(r.zpix, f);
        }
        pk[k] = t;
        validm |= (t != SENT ? 1 : 0) << k;
    }

    const int c0 = __popc(validm);
    int cnt = c0;
    #pragma unroll
    for (int m = 1; m < 64; m <<= 1) cnt += __shfl_xor(cnt, m, 64);

    float nr = 0.0f, ng = 0.0f, nb = 0.0f, dn = 0.0f, ap = 1.0f;
    float zmaxv = EPS_F;

    __shared__ unsigned long long q[4][64];

    if (cnt <= 64) {
        // ---- spread candidates to one-per-lane via wave-private LDS ----
        int pre = c0;
        #pragma unroll
        for (int i = 1; i < 64; i <<= 1) {
            int u = __shfl_up(pre, i, 64);
            if (lane >= i) pre += u;
        }
        pre -= c0;                                  // exclusive prefix
        q[wv][lane] = SENT;
        __builtin_amdgcn_wave_barrier();
        asm volatile("" ::: "memory");
        int o = pre;
        #pragma unroll
        for (int k = 0; k < 8; ++k)
            if (validm & (1 << k)) { q[wv][o] = pk[k]; ++o; }
        __builtin_amdgcn_wave_barrier();
        asm volatile("" ::: "memory");
        unsigned long long v = q[wv][lane];

        // ---- bitonic sort ascending across 64 lanes ----
        #pragma unroll
        for (int kk = 2; kk <= 64; kk <<= 1) {
            #pragma unroll
            for (int j = kk >> 1; j > 0; j >>= 1) {
                unsigned long long o2 = shflx64(v, j);
                bool kmin = ((lane & kk) == 0) == ((lane & j) == 0);
                v = (kmin == (o2 < v)) ? o2 : v;
            }
        }
        if (cnt > 0) {
            unsigned z0b = (unsigned)__shfl((int)(unsigned)(v >> 32), 0, 64);
            zmaxv = fmaxf((ZFAR_F - __uint_as_float(z0b)) / (ZFAR_F - ZNEAR_F), EPS_F);
        }
        const int incn = (cnt < KK) ? cnt : KK;
        if (lane < incn) {
            int f = (int)(v & 0xffffffffull);
            float z = __uint_as_float((unsigned)(v >> 32));
            agg_face(px, py, geop, colp, base + f, z, zmaxv, nr, ng, nb, dn, ap);
        }
    } else {
        // ---- slow path: pop-min 16 rounds over multi-slot lanes ----
        int remm = validm, inclm = 0;
        float zming = 0.0f;
        for (int r = 0; r < 16; ++r) {
            unsigned long long lm = SENT;
            #pragma unroll
            for (int k = 0; k < 8; ++k)
                if (remm & (1 << k)) lm = (pk[k] < lm) ? pk[k] : lm;
            #pragma unroll
            for (int m = 1; m < 64; m <<= 1) {
                unsigned long long o2 = shflx64(lm, m);
                if (o2 < lm) lm = o2;
            }
            if (r == 0) zming = __uint_as_float((unsigned)(lm >> 32));
            #pragma unroll
            for (int k = 0; k < 8; ++k)
                if ((remm & (1 << k)) && pk[k] == lm) { inclm |= 1 << k; remm &= ~(1 << k); }
        }
        zmaxv = fmaxf((ZFAR_F - zming) / (ZFAR_F - ZNEAR_F), EPS_F);
        #pragma unroll
        for (int k = 0; k < 8; ++k)
            if (inclm & (1 << k)) {
                int f = (k << 6) | lane;
                float z = __uint_as_float((unsigned)(pk[k] >> 32));
                agg_face(px, py, geop, colp, base + f, z, zmaxv, nr, ng, nb, dn, ap);
            }
    }

    // ---- wave butterfly reductions (deterministic fixed order) ----
    #pragma unroll
    for (int m = 1; m < 64; m <<= 1) {
        nr += __shfl_xor(nr, m, 64);
        ng += __shfl_xor(ng, m, 64);
        nb += __shfl_xor(nb, m, 64);
        dn += __shfl_xor(dn, m, 64);
        ap *= __shfl_xor(ap, m, 64);
    }
    if (lane == 0) {
        float delta = expf((EPS_F - zmaxv) / GAMMA_F);
        float dd = dn + delta;
        float4 o4;
        o4.x = (nr + delta) / dd;
        o4.y = (ng + delta) / dd;
        o4.z = (nb + delta) / dd;
        o4.w = 1.0f - ap;
        *reinterpret_cast<float4*>(&out[((size_t)b * NPIX + p) * 4]) = o4;
    }
}

// ============ fallback (proven round-5 kernel) for tiny ws ============
#define PIX_PB 32
#define TPP 8
#define FPT (NF/TPP)

__global__ __launch_bounds__(256) void render_kernel_fb(
    const float* __restrict__ mpos, const float* __restrict__ mrot,
    const float* __restrict__ mscale, const float* __restrict__ cpos,
    const float* __restrict__ crot, const float* __restrict__ verts,
    const int* __restrict__ faces, const float* __restrict__ vcol,
    float* __restrict__ out)
{
    __shared__ float4 svp[NV];
    __shared__ unsigned long long cand[TPP][KK][PIX_PB];
    __shared__ int   scnt[TPP][PIX_PB];
    __shared__ float sminz[TPP][PIX_PB];
    __shared__ float spart[5][TPP][PIX_PB];

    const int blocksPerBatch = NPIX / PIX_PB;
    const int b    = blockIdx.x / blocksPerBatch;
    const int tile = blockIdx.x % blocksPerBatch;
    const int tid  = threadIdx.x;
    const int pix  = tid & (PIX_PB - 1);
    const int sub  = tid >> 5;

    float cr[9];
    #pragma unroll
    for (int t = 0; t < 9; ++t) cr[t] = crot[b*9 + t];
    const float cpx = cpos[b*3+0], cpy = cpos[b*3+1], cpz = cpos[b*3+2];

    for (int g = tid; g < NV; g += 256) {
        int m = g >> 8;
        int sb = (b*MM + m)*3;
        float v0 = verts[g*3+0] * mscale[sb+0];
        float v1 = verts[g*3+1] * mscale[sb+1];
        float v2 = verts[g*3+2] * mscale[sb+2];
        int rb = (b*MM + m)*9;
        float wx = mrot[rb+0]*v0 + mrot[rb+1]*v1 + mrot[rb+2]*v2 + mpos[sb+0];
        float wy = mrot[rb+3]*v0 + mrot[rb+4]*v1 + mrot[rb+5]*v2 + mpos[sb+1];
        float wz = mrot[rb+6]*v0 + mrot[rb+7]*v1 + mrot[rb+8]*v2 + mpos[sb+2];
        float cx = wx*cr[0] + wy*cr[3] + wz*cr[6] + cpx;
        float cy = wx*cr[1] + wy*cr[4] + wz*cr[7] + cpy;
        float cz = wx*cr[2] + wy*cr[5] + wz*cr[8] + cpz;
        svp[g] = make_float4(cx / cz, cy / cz, cz, 0.0f);
    }
    __syncthreads();

    const int p  = tile * PIX_PB + pix;
    const int pi = p / WW, pj = p % WW;
    const float px = ((float)pj + 0.5f) * 2.0f / (float)WW - 1.0f;
    const float py = 1.0f - ((float)pi + 0.5f) * 2.0f / (float)HH;

    float topZ[KK]; int topI[KK];
    #pragma unroll
    for (int s = 0; s < KK; ++s) { topZ[s] = INFINITY; topI[s] = -1; }
    float curMax = INFINITY;

    for (int k = 0; k < FPT; ++k) {
        const int f = sub * FPT + k;
        const int moff = (f >> 8) << 8;
        int i0 = faces[f*3+0] + moff;
        int i1 = faces[f*3+1] + moff;
        int i2 = faces[f*3+2] + moff;
        Rast r = rasterize_p(px, py, svp[i0], svp[i1], svp[i2]);
        if ((r.zpix > 0.01f) && (r.dists <= BLUR_F) && (r.zpix < curMax)) {
            float mz = topZ[0]; int mslot = 0;
            #pragma unroll
            for (int s = 1; s < KK; ++s)
                if (topZ[s] > mz) { mz = topZ[s]; mslot = s; }
            #pragma unroll
            for (int s = 0; s < KK; ++s)
                if (s == mslot) { topZ[s] = r.zpix; topI[s] = f; }
            curMax = topZ[0];
            #pragma unroll
            for (int s = 1; s < KK; ++s) curMax = fmaxf(curMax, topZ[s]);
        }
    }

    {
        int c = 0; float mn = INFINITY;
        #pragma unroll
        for (int s = 0; s < KK; ++s)
            if (topI[s] >= 0) { cand[sub][c][pix] = packzf(topZ[s], topI[s]); ++c; mn = fminf(mn, topZ[s]); }
        scnt[sub][pix] = c; sminz[sub][pix] = mn;
    }
    __syncthreads();

    int total = 0;
    #pragma unroll
    for (int s = 0; s < TPP; ++s) total += scnt[s][pix];
    float minz = INFINITY;
    #pragma unroll
    for (int s = 0; s < TPP; ++s) minz = fminf(minz, sminz[s][pix]);
    float zmaxv = EPS_F;
    if (minz < INFINITY) zmaxv = fmaxf((ZFAR_F - minz) / (ZFAR_F - ZNEAR_F), EPS_F);

    float nr = 0, ng = 0, nb = 0, dn = 0, ap = 1.0f;
    #pragma unroll
    for (int s = 0; s < KK; ++s) {
        int f = topI[s];
        if (f < 0) continue;
        bool inc = true;
        if (total > KK) {
            unsigned long long mypk = packzf(topZ[s], f);
            int rank = 0;
            for (int t = 0; t < TPP; ++t) {
                int n = scnt[t][pix];
                for (int j = 0; j < n; ++j) rank += (cand[t][j][pix] < mypk) ? 1 : 0;
            }
            inc = (rank < KK);
        }
        if (!inc) continue;
        const int moff = (f >> 8) << 8;
        int i0 = faces[f*3+0] + moff;
        int i1 = faces[f*3+1] + moff;
        int i2 = faces[f*3+2] + moff;
        Rast r = rasterize_p(px, py, svp[i0], svp[i1], svp[i2]);
        float prob = 1.0f / (1.0f + expf(r.dists / SIGMA_F));
        float zinv = (ZFAR_F - topZ[s]) / (ZFAR_F - ZNEAR_F);
        float w = prob * expf((zinv - zmaxv) / GAMMA_F);
        nr += w * (r.b0*vcol[i0*3+0] + r.b1*vcol[i1*3+0] + r.b2*vcol[i2*3+0]);
        ng += w * (r.b0*vcol[i0*3+1] + r.b1*vcol[i1*3+1] + r.b2*vcol[i2*3+1]);
        nb += w * (r.b0*vcol[i0*3+2] + r.b1*vcol[i1*3+2] + r.b2*vcol[i2*3+2]);
        dn += w; ap *= (1.0f - prob);
    }

    spart[0][sub][pix] = nr; spart[1][sub][pix] = ng; spart[2][sub][pix] = nb;
    spart[3][sub][pix] = dn; spart[4][sub][pix] = ap;
    __syncthreads();

    if (tid < PIX_PB) {
        float rr = 0, gg = 0, bb = 0, dd = 0, aa = 1.0f;
        #pragma unroll
        for (int s = 0; s < TPP; ++s) {
            rr += spart[0][s][tid]; gg += spart[1][s][tid]; bb += spart[2][s][tid];
            dd += spart[3][s][tid]; aa *= spart[4][s][tid];
        }
        float mz = INFINITY;
        #pragma unroll
        for (int s = 0; s < TPP; ++s) mz = fminf(mz, sminz[s][tid]);
        float zmx = EPS_F;
        if (mz < INFINITY) zmx = fmaxf((ZFAR_F - mz) / (ZFAR_F - ZNEAR_F), EPS_F);
        float delta = expf((EPS_F - zmx) / GAMMA_F);
        rr += delta; gg += delta; bb += delta; dd += delta;
        int pp = tile * PIX_PB + tid;
        float4 px4;
        px4.x = rr / dd; px4.y = gg / dd; px4.z = bb / dd; px4.w = 1.0f - aa;
        *reinterpret_cast<float4*>(&out[((size_t)b * NPIX + pp) * 4]) = px4;
    }
}

extern "C" void kernel_launch(void* const* d_in, const int* in_sizes, int n_in,
                              void* d_out, int out_size, void* d_ws, size_t ws_size,
                              hipStream_t stream) {
    const float* mpos   = (const float*)d_in[0];
    const float* mrot   = (const float*)d_in[1];
    const float* mscale = (const float*)d_in[2];
    const float* cpos   = (const float*)d_in[3];
    const float* crot   = (const float*)d_in[4];
    const float* verts  = (const float*)d_in[5];
    const int*   faces  = (const int*)d_in[6];
    const float* vcol   = (const float*)d_in[7];
    float*       out    = (float*)d_out;

    const int B = in_sizes[3] / 3;                     // cam_pos is (B,3)
    const size_t need = (size_t)B * NF * 7 * sizeof(float4);   // bbox + 3 geo + 3 col

    if (ws_size >= need) {
        stage_kernel<<<dim3(B * MM), dim3(256), 0, stream>>>(
            mpos, mrot, mscale, cpos, crot, verts, faces, vcol, (float4*)d_ws);
        render_wave_kernel<<<dim3(B * (NPIX / 4)), dim3(256), 0, stream>>>(
            (const float4*)d_ws, out, B);
    } else {
        render_kernel_fb<<<dim3(B * (NPIX / PIX_PB)), dim3(256), 0, stream>>>(
            mpos, mrot, mscale, cpos, crot, verts, faces, vcol, out);
    }
}